// Round 6
// baseline (341.408 us; speedup 1.0000x reference)
//
#include <hip/hip_runtime.h>
#include <hip/hip_bf16.h>
#include <stdint.h>

// out[M,N] = x[M,K] @ (base + coeff*(2*mask-1))[K,N]
#define M_DIM 8192
#define K_DIM 4096
#define N_DIM 4096
#define NT (K_DIM / 64)   // 64 K-tiles of BK=64

typedef __attribute__((ext_vector_type(8))) short short8;
typedef __attribute__((ext_vector_type(4))) float f32x4;
typedef unsigned short ushort_t;

typedef const __attribute__((address_space(1))) unsigned int as1const_u32;
typedef __attribute__((address_space(3))) unsigned int as3_u32;

__device__ __forceinline__ unsigned short f2bf(float f) {
  unsigned int u = __float_as_uint(f);
  u += 0x7FFF + ((u >> 16) & 1);   // round-to-nearest-even
  return (unsigned short)(u >> 16);
}

// ---------- prep 1: x (f32) -> bf16, vectorized ----------
__global__ void cvt_x_kernel(const float* __restrict__ x,
                             ushort_t* __restrict__ xb, long n8) {
  long i = (long)blockIdx.x * blockDim.x + threadIdx.x;
  long stride = (long)gridDim.x * blockDim.x;
  for (; i < n8; i += stride) {
    const float4* p = (const float4*)(x + i * 8);
    float4 v0 = p[0], v1 = p[1];
    short8 o;
    o[0] = (short)f2bf(v0.x); o[1] = (short)f2bf(v0.y);
    o[2] = (short)f2bf(v0.z); o[3] = (short)f2bf(v0.w);
    o[4] = (short)f2bf(v1.x); o[5] = (short)f2bf(v1.y);
    o[6] = (short)f2bf(v1.z); o[7] = (short)f2bf(v1.w);
    *(short8*)(xb + i * 8) = o;
  }
}

// ---------- prep 2: Wt[n][k] = bf16(base[k][n] + coeff*sign) ----------
__global__ void make_wt_kernel(const float* __restrict__ base,
                               const int* __restrict__ mask,
                               const float* __restrict__ coeffp,
                               ushort_t* __restrict__ wt) {
  __shared__ ushort_t tile[32][33];
  const float c = *coeffp;
  const int n0 = blockIdx.x * 32, k0 = blockIdx.y * 32;
  const int tx = threadIdx.x, ty = threadIdx.y;
#pragma unroll
  for (int r = 0; r < 4; ++r) {
    int k = k0 + ty + r * 8;
    int n = n0 + tx;
    size_t idx = (size_t)k * N_DIM + n;
    float s = mask[idx] ? c : -c;
    tile[ty + r * 8][tx] = f2bf(base[idx] + s);
  }
  __syncthreads();
#pragma unroll
  for (int r = 0; r < 4; ++r) {
    int n = n0 + ty + r * 8;
    int k = k0 + tx;
    wt[(size_t)n * K_DIM + k] = tile[tx][ty + r * 8];
  }
}

// ---------- 256x256 bf16 GEMM: R3 stage/vmcnt scheme + 1-phase-early frag reads ----------
// Stage stream (R3, proven): p1:(t+1,B,h1) p2:(t+1,A,h1) p3:(t+2,A,h0) p4:(t+2,B,h0);
// vmcnt(6) at ends of p1,p2,p4. Fragment reads decoupled one phase ahead of use:
//   P1 reads B.h1<-t      (backing stage forced at p4(t-1)-end)   -> used P2
//   P2 reads A.h1<-t      (forced at p1(t)-end)                   -> used P3,P4
//   P3-end reads A.h0<-t+1 (forced at p2(t)-end)                  -> used P1(t+1)
//   P4-end (after VW6) reads B.h0<-t+1 (forced by that VW6)       -> used P1(t+1)
// Every MFMA cluster consumes frags read >=1 barrier earlier => lgkm satisfied.
// Tail (r2 fix preserved): loop t<NT-2 (all stages real), stage 2 missing halves,
// vmcnt(0)+barrier, two barrier-free peeled tiles.
#define FENCE asm volatile("" ::: "memory")
#define BAR   do { FENCE; __builtin_amdgcn_s_barrier(); FENCE; } while (0)
#define VW6   asm volatile("s_waitcnt vmcnt(6)" ::: "memory")
#define VW4   asm volatile("s_waitcnt vmcnt(4)" ::: "memory")
#define VW0   asm volatile("s_waitcnt vmcnt(0)" ::: "memory")

__global__ __launch_bounds__(512, 2) void gemm_bf16_256(
    const ushort_t* __restrict__ Xb,
    const ushort_t* __restrict__ Wt,
    float* __restrict__ out) {
  __shared__ ushort_t Al[2][256][64];   // 64 KiB
  __shared__ ushort_t Bl[2][256][64];   // 64 KiB

  const int tid = threadIdx.x;
  const int lane = tid & 63;
  const int w = tid >> 6;               // wave 0..7
  const int wm = w >> 2, wn = w & 3;    // 2M x 4N
  const int lrow = lane & 15, kg = lane >> 4;

  // T1: bijective XCD swizzle (512 % 8 == 0)
  const int bid = blockIdx.x;
  const int swz = (bid & 7) * 64 + (bid >> 3);
  const int bm = (swz >> 4) * 256;
  const int bn = (swz & 15) * 256;

  // staging: thread covers half-rows w*8+(lane>>3) and +64; LDS slot lane&7;
  // source chunk = slot ^ (row&7)  (pre-swizzled source; read applies same XOR)
  const int rh0 = w * 8 + (lane >> 3);
  const int srcslot = (lane & 7) ^ ((lane >> 3) & 7);
  const ushort_t* Ag = Xb + (size_t)(bm + rh0) * K_DIM + srcslot * 8;
  const ushort_t* Bg = Wt + (size_t)(bn + rh0) * K_DIM + srcslot * 8;
  char* AlB = (char*)&Al[0][0][0];
  char* BlB = (char*)&Bl[0][0][0];
  const int ldsw = w * 1024;

#define STAGE(Og, Lb, u, h) do {                                                   \
    const ushort_t* _s0 = (Og) + (size_t)((h) * 128) * K_DIM + (size_t)(u) * 64;   \
    __builtin_amdgcn_global_load_lds((as1const_u32*)_s0,                           \
        (as3_u32*)((Lb) + ((u) & 1) * 32768 + (h) * 16384 + ldsw), 16, 0, 0);      \
    __builtin_amdgcn_global_load_lds((as1const_u32*)(_s0 + (size_t)64 * K_DIM),    \
        (as3_u32*)((Lb) + ((u) & 1) * 32768 + (h) * 16384 + ldsw + 8192), 16, 0, 0); \
  } while (0)

  const int arow = (wm * 16 + lrow) << 7;
  const int brow = (wn * 16 + lrow) << 7;
  const int sw0 = ((0 + kg) ^ (lrow & 7)) << 4;
  const int sw1 = ((4 + kg) ^ (lrow & 7)) << 4;

#define LDA(bt, mi, kk) (*(const short8*)(AlB + (bt) * 32768 + (mi) * 4096 + arow + ((kk) ? sw1 : sw0)))
#define LDB(bt, ni, kk) (*(const short8*)(BlB + (bt) * 32768 + (ni) * 8192 + brow + ((kk) ? sw1 : sw0)))
#define MFMA(a, b, c) __builtin_amdgcn_mfma_f32_16x16x32_bf16(a, b, c, 0, 0, 0)

  // fragment register sets (both A halves + both B halves live across phases)
  short8 Ar0[4][2], Ar1[4][2];   // A.h0 (rows 0-127), A.h1 (rows 128-255)
  short8 Br0[2][2], Br1[2][2];   // B.h0 (cols 0-127), B.h1 (cols 128-255)
  f32x4 acc[8][4] = {};

#define RD_A(dst, bt, base)                                                        \
  _Pragma("unroll")                                                                \
  for (int mi = 0; mi < 4; ++mi) {                                                 \
    dst[mi][0] = LDA(bt, (base) + mi, 0); dst[mi][1] = LDA(bt, (base) + mi, 1);    \
  }
#define RD_B(dst, bt, base)                                                        \
  _Pragma("unroll")                                                                \
  for (int ni = 0; ni < 2; ++ni) {                                                 \
    dst[ni][0] = LDB(bt, (base) + ni, 0); dst[ni][1] = LDB(bt, (base) + ni, 1);    \
  }
// 16 MFMA: acc[mb..mb+3][nb..nb+1] += Aset x Bset (K=64 via kk 0,1)
#define MMQ(mb, nb, Aset, Bset)                                                    \
  _Pragma("unroll")                                                                \
  for (int mi = 0; mi < 4; ++mi)                                                   \
    _Pragma("unroll")                                                              \
    for (int ni = 0; ni < 2; ++ni) {                                               \
      acc[(mb) + mi][(nb) + ni] = MFMA(Aset[mi][0], Bset[ni][0], acc[(mb) + mi][(nb) + ni]); \
      acc[(mb) + mi][(nb) + ni] = MFMA(Aset[mi][1], Bset[ni][1], acc[(mb) + mi][(nb) + ni]); \
    }

  // prologue: steady-history stage order; VW4 forces tile-0 complete
  STAGE(Ag, AlB, 0, 0); STAGE(Bg, BlB, 0, 0);
  STAGE(Bg, BlB, 0, 1); STAGE(Ag, AlB, 0, 1);
  STAGE(Ag, AlB, 1, 0); STAGE(Bg, BlB, 1, 0);
  VW4; BAR;
  RD_A(Ar0, 0, 0);   // A.h0 <- tile 0
  RD_B(Br0, 0, 0);   // B.h0 <- tile 0

  for (int t = 0; t < NT - 2; ++t) {
    const int bt = t & 1, bo = bt ^ 1;

    // ---- P1: read B.h1<-t (for P2); stage (t+1,B,h1); MFMA Ar0 x Br0 ----
    RD_B(Br1, bt, 2);
    STAGE(Bg, BlB, t + 1, 1);
    BAR;
    __builtin_amdgcn_s_setprio(1);
    MMQ(0, 0, Ar0, Br0);
    __builtin_amdgcn_s_setprio(0);
    VW6; BAR;

    // ---- P2: read A.h1<-t (for P3/P4); stage (t+1,A,h1); MFMA Ar0 x Br1 ----
    RD_A(Ar1, bt, 4);
    STAGE(Ag, AlB, t + 1, 1);
    BAR;
    __builtin_amdgcn_s_setprio(1);
    MMQ(0, 2, Ar0, Br1);
    __builtin_amdgcn_s_setprio(0);
    VW6; BAR;

    // ---- P3: stage (t+2,A,h0); MFMA Ar1 x Br0; read A.h0<-t+1 (forced @p2-end) ----
    STAGE(Ag, AlB, t + 2, 0);
    BAR;
    __builtin_amdgcn_s_setprio(1);
    MMQ(4, 0, Ar1, Br0);
    __builtin_amdgcn_s_setprio(0);
    RD_A(Ar0, bo, 0);
    BAR;

    // ---- P4: stage (t+2,B,h0); MFMA Ar1 x Br1; VW6; read B.h0<-t+1 ----
    STAGE(Bg, BlB, t + 2, 0);
    BAR;
    __builtin_amdgcn_s_setprio(1);
    MMQ(4, 2, Ar1, Br1);
    __builtin_amdgcn_s_setprio(0);
    VW6;
    RD_B(Br0, bo, 0);
    BAR;
  }

  // ---- tail: stage the 2 missing halves, drain, two barrier-free peeled tiles ----
  STAGE(Bg, BlB, NT - 1, 1);
  STAGE(Ag, AlB, NT - 1, 1);
  VW0; BAR;
  {
    const int bt = (NT - 2) & 1, bl = (NT - 1) & 1;
    // tile NT-2 (Ar0/Br0 already loaded by last loop iter)
    RD_B(Br1, bt, 2);
    RD_A(Ar1, bt, 4);
    MMQ(0, 0, Ar0, Br0);
    MMQ(0, 2, Ar0, Br1);
    MMQ(4, 0, Ar1, Br0);
    MMQ(4, 2, Ar1, Br1);
    // tile NT-1
    RD_A(Ar0, bl, 0);
    RD_B(Br0, bl, 0);
    RD_B(Br1, bl, 2);
    RD_A(Ar1, bl, 4);
    MMQ(0, 0, Ar0, Br0);
    MMQ(0, 2, Ar0, Br1);
    MMQ(4, 0, Ar1, Br0);
    MMQ(4, 2, Ar1, Br1);
  }

  // epilogue: C/D layout col=lane&15, row=(lane>>4)*4+r  [m89/m91]
#pragma unroll
  for (int mi = 0; mi < 8; ++mi)
#pragma unroll
    for (int ni = 0; ni < 4; ++ni) {
      const int gr = bm + mi * 32 + wm * 16 + kg * 4;
      const int gc = bn + ni * 64 + wn * 16 + lrow;
      float* o = out + (size_t)gr * N_DIM + gc;
#pragma unroll
      for (int r = 0; r < 4; ++r) o[(size_t)r * N_DIM] = acc[mi][ni][r];
    }
}

// ---------- fallback (tiny workspace): exact f32 tiled GEMM ----------
__global__ void gemm_f32_fallback(const float* __restrict__ x,
                                  const float* __restrict__ base,
                                  const float* __restrict__ coeffp,
                                  const int* __restrict__ mask,
                                  float* __restrict__ out) {
  __shared__ float As[32][33];
  __shared__ float Bs[32][33];
  const float c = *coeffp;
  const int tx = threadIdx.x, ty = threadIdx.y;
  const int row = blockIdx.y * 32 + ty, col = blockIdx.x * 32 + tx;
  float acc = 0.f;
  for (int kt = 0; kt < K_DIM; kt += 32) {
    As[ty][tx] = x[(size_t)row * K_DIM + kt + tx];
    size_t bidx = (size_t)(kt + ty) * N_DIM + col;
    Bs[ty][tx] = base[bidx] + (mask[bidx] ? c : -c);
    __syncthreads();
#pragma unroll
    for (int k = 0; k < 32; ++k) acc += As[ty][k] * Bs[k][tx];
    __syncthreads();
  }
  out[(size_t)row * N_DIM + col] = acc;
}

extern "C" void kernel_launch(void* const* d_in, const int* in_sizes, int n_in,
                              void* d_out, int out_size, void* d_ws, size_t ws_size,
                              hipStream_t stream) {
  const float* x     = (const float*)d_in[0];
  const float* base  = (const float*)d_in[1];
  const float* coeff = (const float*)d_in[2];
  const int*   mask  = (const int*)d_in[3];
  float* out = (float*)d_out;

  const size_t xb_bytes = (size_t)M_DIM * K_DIM * sizeof(ushort_t);  // 64 MiB
  const size_t wt_bytes = (size_t)K_DIM * N_DIM * sizeof(ushort_t);  // 32 MiB

  if (ws_size >= xb_bytes + wt_bytes) {
    ushort_t* xb = (ushort_t*)d_ws;
    ushort_t* wt = (ushort_t*)((char*)d_ws + xb_bytes);
    long n8 = (long)M_DIM * K_DIM / 8;
    cvt_x_kernel<<<4096, 256, 0, stream>>>(x, xb, n8);
    make_wt_kernel<<<dim3(N_DIM / 32, K_DIM / 32), dim3(32, 8), 0, stream>>>(base, mask, coeff, wt);
    gemm_bf16_256<<<512, 512, 0, stream>>>(xb, wt, out);
  } else {
    gemm_f32_fallback<<<dim3(N_DIM / 32, M_DIM / 32), dim3(32, 32), 0, stream>>>(x, base, coeff, mask, out);
  }
}

// Round 7
// 330.933 us; speedup vs baseline: 1.0317x; 1.0317x over previous
//
#include <hip/hip_runtime.h>
#include <hip/hip_bf16.h>
#include <stdint.h>

// out[M,N] = x[M,K] @ (base + coeff*(2*mask-1))[K,N]
#define M_DIM 8192
#define K_DIM 4096
#define N_DIM 4096
#define NT (K_DIM / 64)   // 64 K-tiles of BK=64

typedef __attribute__((ext_vector_type(8))) short short8;
typedef __attribute__((ext_vector_type(4))) float f32x4;
typedef unsigned short ushort_t;

typedef const __attribute__((address_space(1))) unsigned int as1const_u32;
typedef __attribute__((address_space(3))) unsigned int as3_u32;

__device__ __forceinline__ unsigned short f2bf(float f) {
  unsigned int u = __float_as_uint(f);
  u += 0x7FFF + ((u >> 16) & 1);   // round-to-nearest-even
  return (unsigned short)(u >> 16);
}

// ---------- prep 1: x (f32) -> bf16, vectorized ----------
__global__ void cvt_x_kernel(const float* __restrict__ x,
                             ushort_t* __restrict__ xb, long n8) {
  long i = (long)blockIdx.x * blockDim.x + threadIdx.x;
  long stride = (long)gridDim.x * blockDim.x;
  for (; i < n8; i += stride) {
    const float4* p = (const float4*)(x + i * 8);
    float4 v0 = p[0], v1 = p[1];
    short8 o;
    o[0] = (short)f2bf(v0.x); o[1] = (short)f2bf(v0.y);
    o[2] = (short)f2bf(v0.z); o[3] = (short)f2bf(v0.w);
    o[4] = (short)f2bf(v1.x); o[5] = (short)f2bf(v1.y);
    o[6] = (short)f2bf(v1.z); o[7] = (short)f2bf(v1.w);
    *(short8*)(xb + i * 8) = o;
  }
}

// ---------- prep 2: Wt[n][k] = bf16(base[k][n] + coeff*sign) ----------
__global__ void make_wt_kernel(const float* __restrict__ base,
                               const int* __restrict__ mask,
                               const float* __restrict__ coeffp,
                               ushort_t* __restrict__ wt) {
  __shared__ ushort_t tile[32][33];
  const float c = *coeffp;
  const int n0 = blockIdx.x * 32, k0 = blockIdx.y * 32;
  const int tx = threadIdx.x, ty = threadIdx.y;
#pragma unroll
  for (int r = 0; r < 4; ++r) {
    int k = k0 + ty + r * 8;
    int n = n0 + tx;
    size_t idx = (size_t)k * N_DIM + n;
    float s = mask[idx] ? c : -c;
    tile[ty + r * 8][tx] = f2bf(base[idx] + s);
  }
  __syncthreads();
#pragma unroll
  for (int r = 0; r < 4; ++r) {
    int n = n0 + ty + r * 8;
    int k = k0 + tx;
    wt[(size_t)n * K_DIM + k] = tile[tx][ty + r * 8];
  }
}

// ---------- 256x256 bf16 GEMM: 2-barrier/K-tile, reads streamed under MFMA ----------
// Invariant: after tile-entry BAR, ALL of buffer bt is valid -> all 24 fragment
// ds_reads issue inside the MFMA stream (compiler emits fine-grained lgkmcnt).
// Mid-tile: lgkmcnt(0)+BAR (all waves' reads done) THEN issue 4 STAGEs (t+2 ->
// same buffer bt) + remaining 32 MFMA. Tile-end: vmcnt(8)+BAR forces tile t+1's
// 8 loads (issued mid-tile t-1 -> ~1.5-tile lead). Loop t<NT-2: every stage real
// (counted vmcnt exact). Tail: tile NT-2 stage-free, vmcnt(0)+BAR, tile NT-1.
#define FENCE asm volatile("" ::: "memory")
#define BAR   do { FENCE; __builtin_amdgcn_s_barrier(); FENCE; } while (0)
#define VW8   asm volatile("s_waitcnt vmcnt(8)" ::: "memory")
#define VW0   asm volatile("s_waitcnt vmcnt(0)" ::: "memory")
#define LGK0  asm volatile("s_waitcnt lgkmcnt(0)" ::: "memory")

__global__ __launch_bounds__(512, 2) void gemm_bf16_256(
    const ushort_t* __restrict__ Xb,
    const ushort_t* __restrict__ Wt,
    float* __restrict__ out) {
  __shared__ ushort_t Al[2][256][64];   // 64 KiB
  __shared__ ushort_t Bl[2][256][64];   // 64 KiB

  const int tid = threadIdx.x;
  const int lane = tid & 63;
  const int w = tid >> 6;               // wave 0..7
  const int wm = w >> 2, wn = w & 3;    // 2M x 4N
  const int lrow = lane & 15, kg = lane >> 4;

  // T1: bijective XCD swizzle (512 % 8 == 0)
  const int bid = blockIdx.x;
  const int swz = (bid & 7) * 64 + (bid >> 3);
  const int bm = (swz >> 4) * 256;
  const int bn = (swz & 15) * 256;

  // staging: thread covers half-rows w*8+(lane>>3) and +64; LDS slot lane&7;
  // source chunk = slot ^ (row&7)  (pre-swizzled source; read applies same XOR)
  const int rh0 = w * 8 + (lane >> 3);
  const int srcslot = (lane & 7) ^ ((lane >> 3) & 7);
  const ushort_t* Ag = Xb + (size_t)(bm + rh0) * K_DIM + srcslot * 8;
  const ushort_t* Bg = Wt + (size_t)(bn + rh0) * K_DIM + srcslot * 8;
  char* AlB = (char*)&Al[0][0][0];
  char* BlB = (char*)&Bl[0][0][0];
  const int ldsw = w * 1024;

#define STAGE(Og, Lb, u, h) do {                                                   \
    const ushort_t* _s0 = (Og) + (size_t)((h) * 128) * K_DIM + (size_t)(u) * 64;   \
    __builtin_amdgcn_global_load_lds((as1const_u32*)_s0,                           \
        (as3_u32*)((Lb) + ((u) & 1) * 32768 + (h) * 16384 + ldsw), 16, 0, 0);      \
    __builtin_amdgcn_global_load_lds((as1const_u32*)(_s0 + (size_t)64 * K_DIM),    \
        (as3_u32*)((Lb) + ((u) & 1) * 32768 + (h) * 16384 + ldsw + 8192), 16, 0, 0); \
  } while (0)

  const int arow = (wm * 16 + lrow) << 7;
  const int brow = (wn * 16 + lrow) << 7;
  const int sw0 = ((0 + kg) ^ (lrow & 7)) << 4;
  const int sw1 = ((4 + kg) ^ (lrow & 7)) << 4;

#define LDA(bt, mi, kk) (*(const short8*)(AlB + (bt) * 32768 + (mi) * 4096 + arow + ((kk) ? sw1 : sw0)))
#define LDB(bt, ni, kk) (*(const short8*)(BlB + (bt) * 32768 + (ni) * 8192 + brow + ((kk) ? sw1 : sw0)))
#define MFMA(a, b, c) __builtin_amdgcn_mfma_f32_16x16x32_bf16(a, b, c, 0, 0, 0)

  f32x4 acc[8][4] = {};
  short8 Ar0[4][2], Ar1[4][2];   // A rows mi0-3 (h0), mi4-7 (h1)
  short8 Br0[2][2], Br1[2][2];   // B cols ni0-1 (h0), ni2-3 (h1)

#define RD_A(dst, bt, base)                                                        \
  _Pragma("unroll")                                                                \
  for (int mi = 0; mi < 4; ++mi) {                                                 \
    dst[mi][0] = LDA(bt, (base) + mi, 0); dst[mi][1] = LDA(bt, (base) + mi, 1);    \
  }
#define RD_B(dst, bt, base)                                                        \
  _Pragma("unroll")                                                                \
  for (int ni = 0; ni < 2; ++ni) {                                                 \
    dst[ni][0] = LDB(bt, (base) + ni, 0); dst[ni][1] = LDB(bt, (base) + ni, 1);    \
  }
#define MMQ(mb, nb, Aset, Bset)                                                    \
  _Pragma("unroll")                                                                \
  for (int mi = 0; mi < 4; ++mi)                                                   \
    _Pragma("unroll")                                                              \
    for (int ni = 0; ni < 2; ++ni) {                                               \
      acc[(mb) + mi][(nb) + ni] = MFMA(Aset[mi][0], Bset[ni][0], acc[(mb) + mi][(nb) + ni]); \
      acc[(mb) + mi][(nb) + ni] = MFMA(Aset[mi][1], Bset[ni][1], acc[(mb) + mi][(nb) + ni]); \
    }

  // prologue: stage tiles 0 and 1 fully (16 loads); vmcnt(8) -> tile 0 complete
  STAGE(Ag, AlB, 0, 0); STAGE(Bg, BlB, 0, 0);
  STAGE(Ag, AlB, 0, 1); STAGE(Bg, BlB, 0, 1);
  STAGE(Ag, AlB, 1, 0); STAGE(Bg, BlB, 1, 0);
  STAGE(Ag, AlB, 1, 1); STAGE(Bg, BlB, 1, 1);
  VW8; BAR;

  for (int t = 0; t < NT - 2; ++t) {
    const int bt = t & 1;

    // first half: reads stream under MFMA (compiler fine-grained lgkm waits)
    RD_A(Ar0, bt, 0);
    RD_B(Br0, bt, 0);
    __builtin_amdgcn_s_setprio(1);
    MMQ(0, 0, Ar0, Br0);
    __builtin_amdgcn_s_setprio(0);
    RD_B(Br1, bt, 2);
    RD_A(Ar1, bt, 4);
    __builtin_amdgcn_s_setprio(1);
    MMQ(0, 2, Ar0, Br1);
    __builtin_amdgcn_s_setprio(0);

    // all 24 reads done in every wave -> safe to overwrite buffer bt with t+2
    LGK0; BAR;
    STAGE(Ag, AlB, t + 2, 0); STAGE(Bg, BlB, t + 2, 0);
    STAGE(Ag, AlB, t + 2, 1); STAGE(Bg, BlB, t + 2, 1);

    // second half: pure MFMA (frags already in registers)
    __builtin_amdgcn_s_setprio(1);
    MMQ(4, 0, Ar1, Br0);
    MMQ(4, 2, Ar1, Br1);
    __builtin_amdgcn_s_setprio(0);

    // force tile t+1 (8 oldest of <=16 outstanding); collectivize via barrier
    VW8; BAR;
  }

  // ---- tile NT-2: stage-free ----
  {
    const int bt = (NT - 2) & 1;
    RD_A(Ar0, bt, 0); RD_B(Br0, bt, 0);
    RD_B(Br1, bt, 2); RD_A(Ar1, bt, 4);
    MMQ(0, 0, Ar0, Br0);
    MMQ(0, 2, Ar0, Br1);
    MMQ(4, 0, Ar1, Br0);
    MMQ(4, 2, Ar1, Br1);
  }
  // tile NT-1's DMAs (issued mid tile NT-3) must be fully landed in ALL waves
  VW0; BAR;
  {
    const int bt = (NT - 1) & 1;
    RD_A(Ar0, bt, 0); RD_B(Br0, bt, 0);
    RD_B(Br1, bt, 2); RD_A(Ar1, bt, 4);
    MMQ(0, 0, Ar0, Br0);
    MMQ(0, 2, Ar0, Br1);
    MMQ(4, 0, Ar1, Br0);
    MMQ(4, 2, Ar1, Br1);
  }

  // epilogue: C/D layout col=lane&15, row=(lane>>4)*4+r  [m89/m91]
#pragma unroll
  for (int mi = 0; mi < 8; ++mi)
#pragma unroll
    for (int ni = 0; ni < 4; ++ni) {
      const int gr = bm + mi * 32 + wm * 16 + kg * 4;
      const int gc = bn + ni * 64 + wn * 16 + lrow;
      float* o = out + (size_t)gr * N_DIM + gc;
#pragma unroll
      for (int r = 0; r < 4; ++r) o[(size_t)r * N_DIM] = acc[mi][ni][r];
    }
}

// ---------- fallback (tiny workspace): exact f32 tiled GEMM ----------
__global__ void gemm_f32_fallback(const float* __restrict__ x,
                                  const float* __restrict__ base,
                                  const float* __restrict__ coeffp,
                                  const int* __restrict__ mask,
                                  float* __restrict__ out) {
  __shared__ float As[32][33];
  __shared__ float Bs[32][33];
  const float c = *coeffp;
  const int tx = threadIdx.x, ty = threadIdx.y;
  const int row = blockIdx.y * 32 + ty, col = blockIdx.x * 32 + tx;
  float acc = 0.f;
  for (int kt = 0; kt < K_DIM; kt += 32) {
    As[ty][tx] = x[(size_t)row * K_DIM + kt + tx];
    size_t bidx = (size_t)(kt + ty) * N_DIM + col;
    Bs[ty][tx] = base[bidx] + (mask[bidx] ? c : -c);
    __syncthreads();
#pragma unroll
    for (int k = 0; k < 32; ++k) acc += As[ty][k] * Bs[k][tx];
    __syncthreads();
  }
  out[(size_t)row * N_DIM + col] = acc;
}

extern "C" void kernel_launch(void* const* d_in, const int* in_sizes, int n_in,
                              void* d_out, int out_size, void* d_ws, size_t ws_size,
                              hipStream_t stream) {
  const float* x     = (const float*)d_in[0];
  const float* base  = (const float*)d_in[1];
  const float* coeff = (const float*)d_in[2];
  const int*   mask  = (const int*)d_in[3];
  float* out = (float*)d_out;

  const size_t xb_bytes = (size_t)M_DIM * K_DIM * sizeof(ushort_t);  // 64 MiB
  const size_t wt_bytes = (size_t)K_DIM * N_DIM * sizeof(ushort_t);  // 32 MiB

  if (ws_size >= xb_bytes + wt_bytes) {
    ushort_t* xb = (ushort_t*)d_ws;
    ushort_t* wt = (ushort_t*)((char*)d_ws + xb_bytes);
    long n8 = (long)M_DIM * K_DIM / 8;
    cvt_x_kernel<<<4096, 256, 0, stream>>>(x, xb, n8);
    make_wt_kernel<<<dim3(N_DIM / 32, K_DIM / 32), dim3(32, 8), 0, stream>>>(base, mask, coeff, wt);
    gemm_bf16_256<<<512, 512, 0, stream>>>(xb, wt, out);
  } else {
    gemm_f32_fallback<<<dim3(N_DIM / 32, M_DIM / 32), dim3(32, 32), 0, stream>>>(x, base, coeff, mask, out);
  }
}